// Round 7
// baseline (532.354 us; speedup 1.0000x reference)
//
#include <hip/hip_runtime.h>
#include <hip/hip_bf16.h>
#include <math.h>

#define NEG_SLOPE 0.2f
#define BN_EPS 1e-5f

typedef short bf16x8 __attribute__((ext_vector_type(8)));
typedef float f32x4 __attribute__((ext_vector_type(4)));

// ---- bf16 helpers (raw ushort payload) ------------------------------------
__device__ __forceinline__ float bf2f(unsigned short u) {
  union { unsigned int i; float f; } v;
  v.i = ((unsigned int)u) << 16;
  return v.f;
}
__device__ __forceinline__ unsigned short f2bf(float f) {
  union { unsigned int i; float f; } v;
  v.f = f;
  unsigned int i = v.i;
  unsigned int r = (i + 0x7fffu + ((i >> 16) & 1u)) >> 16;  // RNE
  return (unsigned short)r;
}

// ---------------------------------------------------------------------------
// Dtype detection: flags[0]=1 if floats are bf16; flags[1]=1 if idx int64.
// ---------------------------------------------------------------------------
__global__ __launch_bounds__(256) void detect_kernel(
    const unsigned int* __restrict__ xw, const unsigned int* __restrict__ eiw,
    int E, int* __restrict__ flags) {
  __shared__ int cnt[2];
  if (threadIdx.x < 2) cnt[threadIdx.x] = 0;
  __syncthreads();
  int t = threadIdx.x;
  int inrange = 0;
  for (int i = t; i < 2048; i += 256) {
    unsigned int e = (xw[i] >> 7) & 0xFFu;
    inrange += (e >= 100u && e <= 135u) ? 1 : 0;
  }
  atomicAdd(&cnt[0], inrange);
  int M = min(1024, E / 2);
  int zeros = 0;
  for (int i = t; i < M; i += 256) zeros += (eiw[2 * i + 1] == 0u) ? 1 : 0;
  atomicAdd(&cnt[1], zeros);
  __syncthreads();
  if (t == 0) {
    flags[0] = (cnt[0] > 1536) ? 1 : 0;
    flags[1] = (cnt[1] > M / 2) ? 1 : 0;
  }
}

__global__ __launch_bounds__(256) void canon_x(
    const void* __restrict__ src, unsigned short* __restrict__ dst, int n_real,
    int n_total, const int* __restrict__ flags) {
  int i = blockIdx.x * 256 + threadIdx.x;
  if (i >= n_total) return;
  unsigned short v = 0;
  if (i < n_real)
    v = flags[0] ? ((const unsigned short*)src)[i]
                 : f2bf(((const float*)src)[i]);
  dst[i] = v;
}

// W [K][N] -> Wt [N][K] bf16.
__global__ __launch_bounds__(256) void canon_w_t(
    const void* __restrict__ src, unsigned short* __restrict__ dst, int Kdim,
    int Ndim, const int* __restrict__ flags) {
  int i = blockIdx.x * 256 + threadIdx.x;
  if (i >= Kdim * Ndim) return;
  int k = i / Ndim, n = i - k * Ndim;
  unsigned short v = flags[0] ? ((const unsigned short*)src)[i]
                              : f2bf(((const float*)src)[i]);
  dst[(size_t)n * Kdim + k] = v;
}

__global__ __launch_bounds__(1024) void canon_params(
    const void* s0, const void* s1, const void* s2, const void* s3,
    const void* s4, const void* s5, const void* s6, const void* s7,
    unsigned short* d0, unsigned short* d1, unsigned short* d2,
    unsigned short* d3, unsigned short* d4, unsigned short* d5,
    unsigned short* d6, unsigned short* d7, const int* __restrict__ flags) {
  int b = blockIdx.x, t = threadIdx.x;
  const void* s;
  unsigned short* d;
  int n;
  switch (b) {
    case 0: s = s0; d = d0; n = 1024; break;
    case 1: s = s1; d = d1; n = 1024; break;
    case 2: s = s2; d = d2; n = 1024; break;
    case 3: s = s3; d = d3; n = 1024; break;
    case 4: s = s4; d = d4; n = 1024; break;
    case 5: s = s5; d = d5; n = 128; break;
    case 6: s = s6; d = d6; n = 128; break;
    default: s = s7; d = d7; n = 128; break;
  }
  if (t < n)
    d[t] = flags[0] ? ((const unsigned short*)s)[t]
                    : f2bf(((const float*)s)[t]);
}

__global__ __launch_bounds__(256) void canon_idx(
    const int* __restrict__ ei, int* __restrict__ eis, int* __restrict__ eid,
    int E, const int* __restrict__ flags) {
  int e = blockIdx.x * 256 + threadIdx.x;
  if (e >= E) return;
  if (flags[1]) {
    eis[e] = ei[2 * (size_t)e];
    eid[e] = ei[2 * (size_t)E + 2 * (size_t)e];
  } else {
    eis[e] = ei[e];
    eid[e] = ei[E + e];
  }
}

// ---------------------------------------------------------------------------
// MFMA GEMM v2: C[M, gx*128] = A[M,K] @ Bt[N,K]^T. 128x128 tile, BK=32,
// 4 waves (2x2), 16 MFMA/iter, 1-deep register prefetch of next K-slab.
// TRANSFORM_A: ELU(a*scale+shift) at LDS-write time (HW __expf).
// ---------------------------------------------------------------------------
template <bool TRANSFORM_A, bool OUT_BF16>
__global__ __launch_bounds__(256) void gemm_mfma(
    const unsigned short* __restrict__ A, const unsigned short* __restrict__ Bt,
    void* __restrict__ Cv, int M, int N, int K,
    const float* __restrict__ scale, const float* __restrict__ shift) {
  constexpr int BK = 32;
  constexpr int LDA = BK + 8;
  __shared__ unsigned short As[128 * LDA];
  __shared__ unsigned short Bs[128 * LDA];

  const int m0 = blockIdx.y * 128;
  const int n0 = blockIdx.x * 128;
  const int tid = threadIdx.x;
  const int wid = tid >> 6;
  const int lane = tid & 63;
  const int q = lane >> 4;
  const int r = lane & 15;
  const int wm = (wid >> 1) * 64;
  const int wn = (wid & 1) * 64;

  f32x4 acc[4][4] = {};

  // staging coords (fixed per thread): two rounds of 2048 elems
  const int row0 = (tid * 8) >> 5, col0 = (tid * 8) & 31;
  const int row1 = row0 + 64;  // rd=1: idx += 2048 -> row += 64, same col

  bf16x8 ra[2], rb[2];
  ra[0] = *(const bf16x8*)(A + (size_t)(m0 + row0) * K + col0);
  ra[1] = *(const bf16x8*)(A + (size_t)(m0 + row1) * K + col0);
  rb[0] = *(const bf16x8*)(Bt + (size_t)(n0 + row0) * K + col0);
  rb[1] = *(const bf16x8*)(Bt + (size_t)(n0 + row1) * K + col0);

  for (int k0 = 0; k0 < K; k0 += BK) {
    // write LDS from regs (apply BN+ELU transform for A if requested)
#pragma unroll
    for (int rd = 0; rd < 2; ++rd) {
      int row = rd ? row1 : row0;
      bf16x8 v = ra[rd];
      if (TRANSFORM_A) {
        float scv[8], shv[8];
        *(float4*)&scv[0] = *(const float4*)(scale + k0 + col0);
        *(float4*)&scv[4] = *(const float4*)(scale + k0 + col0 + 4);
        *(float4*)&shv[0] = *(const float4*)(shift + k0 + col0);
        *(float4*)&shv[4] = *(const float4*)(shift + k0 + col0 + 4);
        union { bf16x8 v; unsigned short u[8]; } p;
        p.v = v;
#pragma unroll
        for (int j = 0; j < 8; ++j) {
          float f = bf2f(p.u[j]) * scv[j] + shv[j];
          f = f > 0.f ? f : (__expf(f) - 1.0f);
          p.u[j] = f2bf(f);
        }
        v = p.v;
      }
      *(bf16x8*)(&As[row * LDA + col0]) = v;
      *(bf16x8*)(&Bs[row * LDA + col0]) = rb[rd];
    }
    __syncthreads();

    // prefetch next K-slab into regs (overlaps MFMA below)
    int k1 = k0 + BK;
    if (k1 < K) {
      ra[0] = *(const bf16x8*)(A + (size_t)(m0 + row0) * K + k1 + col0);
      ra[1] = *(const bf16x8*)(A + (size_t)(m0 + row1) * K + k1 + col0);
      rb[0] = *(const bf16x8*)(Bt + (size_t)(n0 + row0) * K + k1 + col0);
      rb[1] = *(const bf16x8*)(Bt + (size_t)(n0 + row1) * K + k1 + col0);
    }

    bf16x8 af[4], bfv[4];
#pragma unroll
    for (int mi = 0; mi < 4; ++mi)
      af[mi] = *(const bf16x8*)(&As[(wm + mi * 16 + r) * LDA + q * 8]);
#pragma unroll
    for (int ni = 0; ni < 4; ++ni)
      bfv[ni] = *(const bf16x8*)(&Bs[(wn + ni * 16 + r) * LDA + q * 8]);
#pragma unroll
    for (int mi = 0; mi < 4; ++mi)
#pragma unroll
      for (int ni = 0; ni < 4; ++ni)
        acc[mi][ni] = __builtin_amdgcn_mfma_f32_16x16x32_bf16(
            af[mi], bfv[ni], acc[mi][ni], 0, 0, 0);
    __syncthreads();
  }

#pragma unroll
  for (int mi = 0; mi < 4; ++mi) {
#pragma unroll
    for (int ni = 0; ni < 4; ++ni) {
#pragma unroll
      for (int i = 0; i < 4; ++i) {
        int row = m0 + wm + mi * 16 + q * 4 + i;
        int col = n0 + wn + ni * 16 + r;
        if (OUT_BF16)
          ((unsigned short*)Cv)[(size_t)row * N + col] = f2bf(acc[mi][ni][i]);
        else
          ((float*)Cv)[(size_t)row * N + col] = acc[mi][ni][i];
      }
    }
  }
}

// ---------------------------------------------------------------------------
// CSR build over dst — parallel 3-phase scan.
// ---------------------------------------------------------------------------
__global__ __launch_bounds__(256) void count_dst(const int* __restrict__ eid,
                                                 int E, int* __restrict__ cnt) {
  int e = blockIdx.x * 256 + threadIdx.x;
  if (e < E) atomicAdd(&cnt[eid[e]], 1);
}

__global__ __launch_bounds__(256) void scan_p1(const int* __restrict__ cnt,
                                               int* __restrict__ bsum, int N) {
  __shared__ int sd[256];
  int b = blockIdx.x, t = threadIdx.x;
  int base = b * 2048;
  int s = 0;
  for (int i = t; i < 2048; i += 256) {
    int idx = base + i;
    if (idx < N) s += cnt[idx];
  }
  sd[t] = s;
  __syncthreads();
  for (int o = 128; o > 0; o >>= 1) {
    if (t < o) sd[t] += sd[t + o];
    __syncthreads();
  }
  if (t == 0) bsum[b] = sd[0];
}

__global__ __launch_bounds__(256) void scan_p2(int* __restrict__ bsum, int nb) {
  __shared__ int sd[256];
  int t = threadIdx.x;
  int own = (t < nb) ? bsum[t] : 0;
  sd[t] = own;
  __syncthreads();
  for (int o = 1; o < 256; o <<= 1) {
    int v = (t >= o) ? sd[t - o] : 0;
    __syncthreads();
    sd[t] += v;
    __syncthreads();
  }
  if (t < nb) bsum[t] = sd[t] - own;  // exclusive
}

__global__ __launch_bounds__(256) void scan_p3(
    const int* __restrict__ cnt, const int* __restrict__ bsum,
    int* __restrict__ offsets, int* __restrict__ cursor, int N) {
  __shared__ int sd[256];
  int b = blockIdx.x, t = threadIdx.x;
  int base = b * 2048 + t * 8;
  int c[8];
  int ts = 0;
#pragma unroll
  for (int j = 0; j < 8; ++j) {
    int idx = base + j;
    c[j] = (idx < N) ? cnt[idx] : 0;
    ts += c[j];
  }
  sd[t] = ts;
  __syncthreads();
  for (int o = 1; o < 256; o <<= 1) {
    int v = (t >= o) ? sd[t - o] : 0;
    __syncthreads();
    sd[t] += v;
    __syncthreads();
  }
  int run = bsum[b] + sd[t] - ts;
#pragma unroll
  for (int j = 0; j < 8; ++j) {
    int idx = base + j;
    if (idx < N) {
      offsets[idx] = run;
      cursor[idx] = run;
      run += c[j];
    }
  }
  if (b == gridDim.x - 1 && t == 255) offsets[N] = bsum[b] + sd[255];
}

// Also records the dst of each sorted slot (needed by edge-weight kernels).
__global__ __launch_bounds__(256) void scatter_src(
    const int* __restrict__ eis, const int* __restrict__ eid, int E,
    int* __restrict__ cursor, int* __restrict__ srcs, int* __restrict__ dsts) {
  int e = blockIdx.x * 256 + threadIdx.x;
  if (e >= E) return;
  int d = eid[e];
  int pos = atomicAdd(&cursor[d], 1);
  srcs[pos] = eis[e];
  dsts[pos] = d;
}

// ---------------------------------------------------------------------------
// Layer-1 scores, one wave per node: lane covers 16 ch; head = lane>>3.
// ---------------------------------------------------------------------------
__global__ __launch_bounds__(256) void scores1_v2(
    const unsigned short* __restrict__ h1, const unsigned short* __restrict__ a_src,
    const unsigned short* __restrict__ a_dst, float* __restrict__ s_src,
    float* __restrict__ s_dst, int N) {
  int n = blockIdx.x * 4 + (threadIdx.x >> 6);
  int lane = threadIdx.x & 63;
  if (n >= N) return;
  const unsigned short* hp = h1 + (size_t)n * 1024 + lane * 16;
  union { bf16x8 v; unsigned short u[8]; } h0, h1v, s0, s1, d0, d1;
  h0.v = *(const bf16x8*)hp;
  h1v.v = *(const bf16x8*)(hp + 8);
  s0.v = *(const bf16x8*)(a_src + lane * 16);
  s1.v = *(const bf16x8*)(a_src + lane * 16 + 8);
  d0.v = *(const bf16x8*)(a_dst + lane * 16);
  d1.v = *(const bf16x8*)(a_dst + lane * 16 + 8);
  float vs = 0.f, vd = 0.f;
#pragma unroll
  for (int j = 0; j < 8; ++j) {
    float a = bf2f(h0.u[j]), b = bf2f(h1v.u[j]);
    vs += a * bf2f(s0.u[j]) + b * bf2f(s1.u[j]);
    vd += a * bf2f(d0.u[j]) + b * bf2f(d1.u[j]);
  }
  vs += __shfl_xor(vs, 1, 64); vd += __shfl_xor(vd, 1, 64);
  vs += __shfl_xor(vs, 2, 64); vd += __shfl_xor(vd, 2, 64);
  vs += __shfl_xor(vs, 4, 64); vd += __shfl_xor(vd, 4, 64);
  if ((lane & 7) == 0) {
    int h = lane >> 3;
    s_src[n * 8 + h] = vs;
    s_dst[n * 8 + h] = vd;
  }
}

// Layer-2 scores: h2 fp32, H=1.
__global__ __launch_bounds__(256) void scores2_f32(
    const float* __restrict__ h2, const unsigned short* __restrict__ a_src,
    const unsigned short* __restrict__ a_dst, float* __restrict__ s_src,
    float* __restrict__ s_dst, int N) {
  int w = blockIdx.x * 4 + (threadIdx.x >> 6);
  int lane = threadIdx.x & 63;
  if (w >= N) return;
  float2 hv = *(const float2*)(h2 + (size_t)w * 128 + lane * 2);
  unsigned int av = *(const unsigned int*)(a_src + lane * 2);
  unsigned int dv = *(const unsigned int*)(a_dst + lane * 2);
  float vs = hv.x * bf2f(av & 0xffff) + hv.y * bf2f(av >> 16);
  float vd = hv.x * bf2f(dv & 0xffff) + hv.y * bf2f(dv >> 16);
#pragma unroll
  for (int off = 32; off > 0; off >>= 1) {
    vs += __shfl_down(vs, off, 64);
    vd += __shfl_down(vd, off, 64);
  }
  if (lane == 0) {
    s_src[w] = vs;
    s_dst[w] = vd;
  }
}

// ---------------------------------------------------------------------------
// Per-edge softmax numerators, computed ONCE per (edge, head).
// ---------------------------------------------------------------------------
__global__ __launch_bounds__(256) void edge_w1(
    const int* __restrict__ srcs, const int* __restrict__ dsts,
    const float* __restrict__ ssrc, const float* __restrict__ sdst,
    float* __restrict__ ew, int E8) {
  int t = blockIdx.x * 256 + threadIdx.x;
  if (t >= E8) return;
  int p = t >> 3, h = t & 7;
  float v = ssrc[srcs[p] * 8 + h] + sdst[dsts[p] * 8 + h];
  v = v > 0.f ? v : NEG_SLOPE * v;
  ew[t] = __expf(v);
}

__global__ __launch_bounds__(256) void edge_w2(
    const int* __restrict__ srcs, const int* __restrict__ dsts,
    const float* __restrict__ ssrc, const float* __restrict__ sdst,
    float* __restrict__ ew2, int E) {
  int p = blockIdx.x * 256 + threadIdx.x;
  if (p >= E) return;
  float v = ssrc[srcs[p]] + sdst[dsts[p]];
  v = v > 0.f ? v : NEG_SLOPE * v;
  ew2[p] = __expf(v);
}

// ---------------------------------------------------------------------------
// Layer-1 aggregation (CSR, block per dst node, 256 threads, 4 ch/thread).
// Weights precomputed in ew; broadcast-load per edge.
// ---------------------------------------------------------------------------
__global__ __launch_bounds__(256) void agg1_csr(
    const int* __restrict__ offsets, const int* __restrict__ srcs,
    const unsigned short* __restrict__ h1, const float* __restrict__ ew,
    const unsigned short* __restrict__ b1, unsigned short* __restrict__ h1n) {
  int n = blockIdx.x;
  int j = threadIdx.x;
  int c = j * 4;
  int h = c >> 7;
  int beg = offsets[n], end = offsets[n + 1];
  float a0 = 0.f, a1 = 0.f, a2 = 0.f, a3 = 0.f, wsum = 0.f;
  for (int p = beg; p < end; ++p) {
    int s = srcs[p];
    float w = ew[p * 8 + h];
    wsum += w;
    ushort4 u = *(const ushort4*)(h1 + (size_t)s * 1024 + c);
    a0 = fmaf(bf2f(u.x), w, a0);
    a1 = fmaf(bf2f(u.y), w, a1);
    a2 = fmaf(bf2f(u.z), w, a2);
    a3 = fmaf(bf2f(u.w), w, a3);
  }
  float inv = 1.0f / (wsum + 1e-16f);
  ushort4 bb = *(const ushort4*)(b1 + c);
  ushort4 o;
  o.x = f2bf(a0 * inv + bf2f(bb.x));
  o.y = f2bf(a1 * inv + bf2f(bb.y));
  o.z = f2bf(a2 * inv + bf2f(bb.z));
  o.w = f2bf(a3 * inv + bf2f(bb.w));
  *(ushort4*)(h1n + (size_t)n * 1024 + c) = o;
}

// ---------------------------------------------------------------------------
// BN partial sums over h1n (bf16). 32 rows/block -> 1563 blocks.
// ---------------------------------------------------------------------------
__global__ __launch_bounds__(256) void bn_stats(
    const unsigned short* __restrict__ h1n, float* __restrict__ bnsum,
    float* __restrict__ bnsumsq, int N, int rowsPerBlock) {
  int r0 = blockIdx.x * rowsPerBlock;
  int r1 = min(r0 + rowsPerBlock, N);
  int c = threadIdx.x * 4;
  float s0 = 0, s1 = 0, s2 = 0, s3 = 0;
  float q0 = 0, q1 = 0, q2 = 0, q3 = 0;
  for (int r = r0; r < r1; ++r) {
    ushort4 u = *(const ushort4*)(h1n + (size_t)r * 1024 + c);
    float v0 = bf2f(u.x), v1 = bf2f(u.y), v2 = bf2f(u.z), v3 = bf2f(u.w);
    s0 += v0; s1 += v1; s2 += v2; s3 += v3;
    q0 += v0 * v0; q1 += v1 * v1; q2 += v2 * v2; q3 += v3 * v3;
  }
  atomicAdd(&bnsum[c + 0], s0);
  atomicAdd(&bnsum[c + 1], s1);
  atomicAdd(&bnsum[c + 2], s2);
  atomicAdd(&bnsum[c + 3], s3);
  atomicAdd(&bnsumsq[c + 0], q0);
  atomicAdd(&bnsumsq[c + 1], q1);
  atomicAdd(&bnsumsq[c + 2], q2);
  atomicAdd(&bnsumsq[c + 3], q3);
}

__global__ __launch_bounds__(1024) void bn_finalize(
    const float* __restrict__ bnsum, const float* __restrict__ bnsumsq,
    const unsigned short* __restrict__ gamma,
    const unsigned short* __restrict__ beta, float* __restrict__ scale,
    float* __restrict__ shift, int N) {
  int j = threadIdx.x;
  float inv_n = 1.0f / (float)N;
  float mu = bnsum[j] * inv_n;
  float var = bnsumsq[j] * inv_n - mu * mu;
  float sc = bf2f(gamma[j]) * rsqrtf(var + BN_EPS);
  scale[j] = sc;
  shift[j] = bf2f(beta[j]) - mu * sc;
}

// ---------------------------------------------------------------------------
// Layer-2 aggregation (CSR, one wave per dst, 2 ch/lane), ew2 precomputed.
// ---------------------------------------------------------------------------
__global__ __launch_bounds__(64) void agg2_csr(
    const int* __restrict__ offsets, const int* __restrict__ srcs,
    const float* __restrict__ h2, const float* __restrict__ ew2,
    const unsigned short* __restrict__ b2, void* __restrict__ out,
    const int* __restrict__ flags) {
  int n = blockIdx.x;
  int lane = threadIdx.x;
  int c = lane * 2;
  int beg = offsets[n], end = offsets[n + 1];
  float a0 = 0.f, a1 = 0.f, wsum = 0.f;
  for (int p = beg; p < end; ++p) {
    int s = srcs[p];
    float w = ew2[p];
    wsum += w;
    float2 hv = *(const float2*)(h2 + (size_t)s * 128 + c);
    a0 = fmaf(hv.x, w, a0);
    a1 = fmaf(hv.y, w, a1);
  }
  float inv = 1.0f / (wsum + 1e-16f);
  unsigned int bb = *(const unsigned int*)(b2 + c);
  float r0 = a0 * inv + bf2f(bb & 0xffff);
  float r1 = a1 * inv + bf2f(bb >> 16);
  if (flags[0]) {
    unsigned int o = (unsigned int)f2bf(r0) | ((unsigned int)f2bf(r1) << 16);
    *(unsigned int*)((unsigned short*)out + (size_t)n * 128 + c) = o;
  } else {
    *(float2*)((float*)out + (size_t)n * 128 + c) = make_float2(r0, r1);
  }
}

// ---------------------------------------------------------------------------
extern "C" void kernel_launch(void* const* d_in, const int* in_sizes, int n_in,
                              void* d_out, int out_size, void* d_ws,
                              size_t ws_size, hipStream_t stream) {
  const void* x      = d_in[0];
  const int*  ei     = (const int*)d_in[1];
  const void* W1     = d_in[2];
  const void* a_src1 = d_in[3];
  const void* a_dst1 = d_in[4];
  const void* b1     = d_in[5];
  const void* gamma  = d_in[6];
  const void* beta   = d_in[7];
  const void* W2     = d_in[8];
  const void* a_src2 = d_in[9];
  const void* a_dst2 = d_in[10];
  const void* b2     = d_in[11];

  const int N = in_sizes[0] / 128;            // 50000
  const int E = in_sizes[1] / 2;              // 150000
  const int MP = ((N + 127) / 128) * 128;     // 50048
  const int NB = (N + 2047) / 2048;           // scan chunks

  // ---- workspace layout (bytes) ----
  char* ws = (char*)d_ws;
  size_t off = 0;
  unsigned short* h1  = (unsigned short*)(ws + off); off += (size_t)MP * 1024 * 2;
  char* h1n_base = ws + off;
  unsigned short* h1n = (unsigned short*)h1n_base;   off += (size_t)MP * 1024 * 2;
  float* ssrc1 = (float*)(ws + off); off += (size_t)N * 8 * 4;
  float* sdst1 = (float*)(ws + off); off += (size_t)N * 8 * 4;
  int* offsets = (int*)(ws + off); off += ((size_t)(N + 1) * 4 + 63) & ~63ull;
  int* srcs    = (int*)(ws + off); off += (size_t)E * 4;
  int* dsts    = (int*)(ws + off); off += (size_t)E * 4;
  float* ew    = (float*)(ws + off); off += (size_t)E * 8 * 4;  // ew2 aliases
  unsigned short* W1t = (unsigned short*)(ws + off); off += 131072 * 2;
  unsigned short* W2t = (unsigned short*)(ws + off); off += 131072 * 2;
  unsigned short* as1c = (unsigned short*)(ws + off); off += 1024 * 2;
  unsigned short* ad1c = (unsigned short*)(ws + off); off += 1024 * 2;
  unsigned short* b1c  = (unsigned short*)(ws + off); off += 1024 * 2;
  unsigned short* gmc  = (unsigned short*)(ws + off); off += 1024 * 2;
  unsigned short* btc  = (unsigned short*)(ws + off); off += 1024 * 2;
  unsigned short* as2c = (unsigned short*)(ws + off); off += 128 * 2;
  unsigned short* ad2c = (unsigned short*)(ws + off); off += 128 * 2;
  unsigned short* b2c  = (unsigned short*)(ws + off); off += 128 * 2;
  float* bns1  = (float*)(ws + off); off += 1024 * 4;
  float* bns2  = (float*)(ws + off); off += 1024 * 4;
  float* scale = (float*)(ws + off); off += 1024 * 4;
  float* shift = (float*)(ws + off); off += 1024 * 4;
  int* bsum    = (int*)(ws + off); off += 256 * 4;
  int* flags   = (int*)(ws + off); off += 64;
  // Aliases into dead regions (h1n's first ~18.5 MB; all dead before agg1
  // writes h1n; h1n pad rows are at the END of the buffer).
  unsigned short* x_bf = (unsigned short*)h1n_base;
  int* eis    = (int*)(h1n_base + (16u << 20));
  int* eid    = eis + E;
  int* cnt    = eid + E;
  int* cursor = cnt + N;
  // h2 (fp32 [MP][128] = 25.6 MB) aliases h1 (dead after agg1).
  float* h2    = (float*)h1;
  float* ssrc2 = ssrc1;
  float* sdst2 = sdst1;
  float* ew2   = ew;

  // ---- detection + canonicalization ----
  detect_kernel<<<1, 256, 0, stream>>>((const unsigned int*)x,
                                       (const unsigned int*)ei, E, flags);
  canon_x<<<(MP * 128 + 255) / 256, 256, 0, stream>>>(x, x_bf, N * 128,
                                                      MP * 128, flags);
  canon_w_t<<<(131072 + 255) / 256, 256, 0, stream>>>(W1, W1t, 128, 1024, flags);
  canon_w_t<<<(131072 + 255) / 256, 256, 0, stream>>>(W2, W2t, 1024, 128, flags);
  canon_params<<<8, 1024, 0, stream>>>(a_src1, a_dst1, b1, gamma, beta, a_src2,
                                       a_dst2, b2, as1c, ad1c, b1c, gmc, btc,
                                       as2c, ad2c, b2c, flags);
  canon_idx<<<(E + 255) / 256, 256, 0, stream>>>(ei, eis, eid, E, flags);

  // ---- zero init ----
  hipMemsetAsync(cnt, 0, (size_t)N * 4, stream);
  hipMemsetAsync(bns1, 0, 2048 * 4, stream);
  hipMemsetAsync((char*)h1n + (size_t)N * 1024 * 2, 0,
                 (size_t)(MP - N) * 1024 * 2, stream);

  // ---- CSR build (dst-sorted), parallel scan ----
  count_dst<<<(E + 255) / 256, 256, 0, stream>>>(eid, E, cnt);
  scan_p1<<<NB, 256, 0, stream>>>(cnt, bsum, N);
  scan_p2<<<1, 256, 0, stream>>>(bsum, NB);
  scan_p3<<<NB, 256, 0, stream>>>(cnt, bsum, offsets, cursor, N);
  scatter_src<<<(E + 255) / 256, 256, 0, stream>>>(eis, eid, E, cursor, srcs,
                                                   dsts);

  // ---- Layer 1: h1 = x @ W1 (MFMA 128x128, prefetch) ----
  {
    dim3 g(1024 / 128, MP / 128);
    gemm_mfma<false, true><<<g, 256, 0, stream>>>(x_bf, W1t, h1, MP, 1024, 128,
                                                  nullptr, nullptr);
  }
  scores1_v2<<<(N + 3) / 4, 256, 0, stream>>>(h1, as1c, ad1c, ssrc1, sdst1, N);
  edge_w1<<<(E * 8 + 255) / 256, 256, 0, stream>>>(srcs, dsts, ssrc1, sdst1,
                                                   ew, E * 8);
  agg1_csr<<<N, 256, 0, stream>>>(offsets, srcs, h1, ew, b1c, h1n);

  bn_stats<<<(N + 31) / 32, 256, 0, stream>>>(h1n, bns1, bns2, N, 32);
  bn_finalize<<<1, 1024, 0, stream>>>(bns1, bns2, gmc, btc, scale, shift, N);

  // ---- Layer 2: h2 = ELU(BN(h1n)) @ W2 (BN+ELU fused into A staging) ----
  {
    dim3 g(1, MP / 128);
    gemm_mfma<true, false><<<g, 256, 0, stream>>>(h1n, W2t, h2, MP, 128, 1024,
                                                  scale, shift);
  }
  scores2_f32<<<(N + 3) / 4, 256, 0, stream>>>(h2, as2c, ad2c, ssrc2, sdst2, N);
  edge_w2<<<(E + 255) / 256, 256, 0, stream>>>(srcs, dsts, ssrc2, sdst2, ew2, E);
  agg2_csr<<<N, 64, 0, stream>>>(offsets, srcs, h2, ew2, b2c, d_out, flags);
}

// Round 8
// 450.073 us; speedup vs baseline: 1.1828x; 1.1828x over previous
//
#include <hip/hip_runtime.h>
#include <hip/hip_bf16.h>
#include <math.h>

#define NEG_SLOPE 0.2f
#define BN_EPS 1e-5f

typedef short bf16x8 __attribute__((ext_vector_type(8)));
typedef float f32x4 __attribute__((ext_vector_type(4)));

// ---- bf16 helpers (raw ushort payload) ------------------------------------
__device__ __forceinline__ float bf2f(unsigned short u) {
  union { unsigned int i; float f; } v;
  v.i = ((unsigned int)u) << 16;
  return v.f;
}
__device__ __forceinline__ unsigned short f2bf(float f) {
  union { unsigned int i; float f; } v;
  v.f = f;
  unsigned int i = v.i;
  unsigned int r = (i + 0x7fffu + ((i >> 16) & 1u)) >> 16;  // RNE
  return (unsigned short)r;
}

// ---------------------------------------------------------------------------
// Dtype detection: flags[0]=1 if floats are bf16; flags[1]=1 if idx int64.
// ---------------------------------------------------------------------------
__global__ __launch_bounds__(256) void detect_kernel(
    const unsigned int* __restrict__ xw, const unsigned int* __restrict__ eiw,
    int E, int* __restrict__ flags) {
  __shared__ int cnt[2];
  if (threadIdx.x < 2) cnt[threadIdx.x] = 0;
  __syncthreads();
  int t = threadIdx.x;
  int inrange = 0;
  for (int i = t; i < 2048; i += 256) {
    unsigned int e = (xw[i] >> 7) & 0xFFu;
    inrange += (e >= 100u && e <= 135u) ? 1 : 0;
  }
  atomicAdd(&cnt[0], inrange);
  int M = min(1024, E / 2);
  int zeros = 0;
  for (int i = t; i < M; i += 256) zeros += (eiw[2 * i + 1] == 0u) ? 1 : 0;
  atomicAdd(&cnt[1], zeros);
  __syncthreads();
  if (t == 0) {
    flags[0] = (cnt[0] > 1536) ? 1 : 0;
    flags[1] = (cnt[1] > M / 2) ? 1 : 0;
  }
}

__global__ __launch_bounds__(256) void canon_x(
    const void* __restrict__ src, unsigned short* __restrict__ dst, int n_real,
    int n_total, const int* __restrict__ flags) {
  int i = blockIdx.x * 256 + threadIdx.x;
  if (i >= n_total) return;
  unsigned short v = 0;
  if (i < n_real)
    v = flags[0] ? ((const unsigned short*)src)[i]
                 : f2bf(((const float*)src)[i]);
  dst[i] = v;
}

// W [K][N] -> Wt [N][K] bf16.
__global__ __launch_bounds__(256) void canon_w_t(
    const void* __restrict__ src, unsigned short* __restrict__ dst, int Kdim,
    int Ndim, const int* __restrict__ flags) {
  int i = blockIdx.x * 256 + threadIdx.x;
  if (i >= Kdim * Ndim) return;
  int k = i / Ndim, n = i - k * Ndim;
  unsigned short v = flags[0] ? ((const unsigned short*)src)[i]
                              : f2bf(((const float*)src)[i]);
  dst[(size_t)n * Kdim + k] = v;
}

__global__ __launch_bounds__(1024) void canon_params(
    const void* s0, const void* s1, const void* s2, const void* s3,
    const void* s4, const void* s5, const void* s6, const void* s7,
    unsigned short* d0, unsigned short* d1, unsigned short* d2,
    unsigned short* d3, unsigned short* d4, unsigned short* d5,
    unsigned short* d6, unsigned short* d7, const int* __restrict__ flags) {
  int b = blockIdx.x, t = threadIdx.x;
  const void* s;
  unsigned short* d;
  int n;
  switch (b) {
    case 0: s = s0; d = d0; n = 1024; break;
    case 1: s = s1; d = d1; n = 1024; break;
    case 2: s = s2; d = d2; n = 1024; break;
    case 3: s = s3; d = d3; n = 1024; break;
    case 4: s = s4; d = d4; n = 1024; break;
    case 5: s = s5; d = d5; n = 128; break;
    case 6: s = s6; d = d6; n = 128; break;
    default: s = s7; d = d7; n = 128; break;
  }
  if (t < n)
    d[t] = flags[0] ? ((const unsigned short*)s)[t]
                    : f2bf(((const float*)s)[t]);
}

__global__ __launch_bounds__(256) void canon_idx(
    const int* __restrict__ ei, int* __restrict__ eis, int* __restrict__ eid,
    int E, const int* __restrict__ flags) {
  int e = blockIdx.x * 256 + threadIdx.x;
  if (e >= E) return;
  if (flags[1]) {
    eis[e] = ei[2 * (size_t)e];
    eid[e] = ei[2 * (size_t)E + 2 * (size_t)e];
  } else {
    eis[e] = ei[e];
    eid[e] = ei[E + e];
  }
}

// ---------------------------------------------------------------------------
// MFMA GEMM: C[M, gx*128] = A[M,K] @ Bt[N,K]^T. 128x128 tile, BK=32,
// 4 waves (2x2), 16 MFMA/iter, 1-deep register prefetch of next K-slab.
// TRANSFORM_A: ELU(a*scale+shift) at LDS-write time (HW __expf).
// ---------------------------------------------------------------------------
template <bool TRANSFORM_A, bool OUT_BF16>
__global__ __launch_bounds__(256) void gemm_mfma(
    const unsigned short* __restrict__ A, const unsigned short* __restrict__ Bt,
    void* __restrict__ Cv, int M, int N, int K,
    const float* __restrict__ scale, const float* __restrict__ shift) {
  constexpr int BK = 32;
  constexpr int LDA = BK + 8;
  __shared__ unsigned short As[128 * LDA];
  __shared__ unsigned short Bs[128 * LDA];

  const int m0 = blockIdx.y * 128;
  const int n0 = blockIdx.x * 128;
  const int tid = threadIdx.x;
  const int wid = tid >> 6;
  const int lane = tid & 63;
  const int q = lane >> 4;
  const int r = lane & 15;
  const int wm = (wid >> 1) * 64;
  const int wn = (wid & 1) * 64;

  f32x4 acc[4][4] = {};

  const int row0 = (tid * 8) >> 5, col0 = (tid * 8) & 31;
  const int row1 = row0 + 64;

  bf16x8 ra[2], rb[2];
  ra[0] = *(const bf16x8*)(A + (size_t)(m0 + row0) * K + col0);
  ra[1] = *(const bf16x8*)(A + (size_t)(m0 + row1) * K + col0);
  rb[0] = *(const bf16x8*)(Bt + (size_t)(n0 + row0) * K + col0);
  rb[1] = *(const bf16x8*)(Bt + (size_t)(n0 + row1) * K + col0);

  for (int k0 = 0; k0 < K; k0 += BK) {
#pragma unroll
    for (int rd = 0; rd < 2; ++rd) {
      int row = rd ? row1 : row0;
      bf16x8 v = ra[rd];
      if (TRANSFORM_A) {
        float scv[8], shv[8];
        *(float4*)&scv[0] = *(const float4*)(scale + k0 + col0);
        *(float4*)&scv[4] = *(const float4*)(scale + k0 + col0 + 4);
        *(float4*)&shv[0] = *(const float4*)(shift + k0 + col0);
        *(float4*)&shv[4] = *(const float4*)(shift + k0 + col0 + 4);
        union { bf16x8 v; unsigned short u[8]; } p;
        p.v = v;
#pragma unroll
        for (int j = 0; j < 8; ++j) {
          float f = bf2f(p.u[j]) * scv[j] + shv[j];
          f = f > 0.f ? f : (__expf(f) - 1.0f);
          p.u[j] = f2bf(f);
        }
        v = p.v;
      }
      *(bf16x8*)(&As[row * LDA + col0]) = v;
      *(bf16x8*)(&Bs[row * LDA + col0]) = rb[rd];
    }
    __syncthreads();

    int k1 = k0 + BK;
    if (k1 < K) {
      ra[0] = *(const bf16x8*)(A + (size_t)(m0 + row0) * K + k1 + col0);
      ra[1] = *(const bf16x8*)(A + (size_t)(m0 + row1) * K + k1 + col0);
      rb[0] = *(const bf16x8*)(Bt + (size_t)(n0 + row0) * K + k1 + col0);
      rb[1] = *(const bf16x8*)(Bt + (size_t)(n0 + row1) * K + k1 + col0);
    }

    bf16x8 af[4], bfv[4];
#pragma unroll
    for (int mi = 0; mi < 4; ++mi)
      af[mi] = *(const bf16x8*)(&As[(wm + mi * 16 + r) * LDA + q * 8]);
#pragma unroll
    for (int ni = 0; ni < 4; ++ni)
      bfv[ni] = *(const bf16x8*)(&Bs[(wn + ni * 16 + r) * LDA + q * 8]);
#pragma unroll
    for (int mi = 0; mi < 4; ++mi)
#pragma unroll
      for (int ni = 0; ni < 4; ++ni)
        acc[mi][ni] = __builtin_amdgcn_mfma_f32_16x16x32_bf16(
            af[mi], bfv[ni], acc[mi][ni], 0, 0, 0);
    __syncthreads();
  }

#pragma unroll
  for (int mi = 0; mi < 4; ++mi) {
#pragma unroll
    for (int ni = 0; ni < 4; ++ni) {
#pragma unroll
      for (int i = 0; i < 4; ++i) {
        int row = m0 + wm + mi * 16 + q * 4 + i;
        int col = n0 + wn + ni * 16 + r;
        if (OUT_BF16)
          ((unsigned short*)Cv)[(size_t)row * N + col] = f2bf(acc[mi][ni][i]);
        else
          ((float*)Cv)[(size_t)row * N + col] = acc[mi][ni][i];
      }
    }
  }
}

// ---------------------------------------------------------------------------
// CSR build over dst — parallel 3-phase scan.
// ---------------------------------------------------------------------------
__global__ __launch_bounds__(256) void count_dst(const int* __restrict__ eid,
                                                 int E, int* __restrict__ cnt) {
  int e = blockIdx.x * 256 + threadIdx.x;
  if (e < E) atomicAdd(&cnt[eid[e]], 1);
}

__global__ __launch_bounds__(256) void scan_p1(const int* __restrict__ cnt,
                                               int* __restrict__ bsum, int N) {
  __shared__ int sd[256];
  int b = blockIdx.x, t = threadIdx.x;
  int base = b * 2048;
  int s = 0;
  for (int i = t; i < 2048; i += 256) {
    int idx = base + i;
    if (idx < N) s += cnt[idx];
  }
  sd[t] = s;
  __syncthreads();
  for (int o = 128; o > 0; o >>= 1) {
    if (t < o) sd[t] += sd[t + o];
    __syncthreads();
  }
  if (t == 0) bsum[b] = sd[0];
}

__global__ __launch_bounds__(256) void scan_p2(int* __restrict__ bsum, int nb) {
  __shared__ int sd[256];
  int t = threadIdx.x;
  int own = (t < nb) ? bsum[t] : 0;
  sd[t] = own;
  __syncthreads();
  for (int o = 1; o < 256; o <<= 1) {
    int v = (t >= o) ? sd[t - o] : 0;
    __syncthreads();
    sd[t] += v;
    __syncthreads();
  }
  if (t < nb) bsum[t] = sd[t] - own;  // exclusive
}

__global__ __launch_bounds__(256) void scan_p3(
    const int* __restrict__ cnt, const int* __restrict__ bsum,
    int* __restrict__ offsets, int* __restrict__ cursor, int N) {
  __shared__ int sd[256];
  int b = blockIdx.x, t = threadIdx.x;
  int base = b * 2048 + t * 8;
  int c[8];
  int ts = 0;
#pragma unroll
  for (int j = 0; j < 8; ++j) {
    int idx = base + j;
    c[j] = (idx < N) ? cnt[idx] : 0;
    ts += c[j];
  }
  sd[t] = ts;
  __syncthreads();
  for (int o = 1; o < 256; o <<= 1) {
    int v = (t >= o) ? sd[t - o] : 0;
    __syncthreads();
    sd[t] += v;
    __syncthreads();
  }
  int run = bsum[b] + sd[t] - ts;
#pragma unroll
  for (int j = 0; j < 8; ++j) {
    int idx = base + j;
    if (idx < N) {
      offsets[idx] = run;
      cursor[idx] = run;
      run += c[j];
    }
  }
  if (b == gridDim.x - 1 && t == 255) offsets[N] = bsum[b] + sd[255];
}

__global__ __launch_bounds__(256) void scatter_src(
    const int* __restrict__ eis, const int* __restrict__ eid, int E,
    int* __restrict__ cursor, int* __restrict__ srcs, int* __restrict__ dsts) {
  int e = blockIdx.x * 256 + threadIdx.x;
  if (e >= E) return;
  int d = eid[e];
  int pos = atomicAdd(&cursor[d], 1);
  srcs[pos] = eis[e];
  dsts[pos] = d;
}

// ---------------------------------------------------------------------------
// Layer-1 scores, one wave per node: lane covers 16 ch; head = lane>>3.
// ---------------------------------------------------------------------------
__global__ __launch_bounds__(256) void scores1_v2(
    const unsigned short* __restrict__ h1, const unsigned short* __restrict__ a_src,
    const unsigned short* __restrict__ a_dst, float* __restrict__ s_src,
    float* __restrict__ s_dst, int N) {
  int n = blockIdx.x * 4 + (threadIdx.x >> 6);
  int lane = threadIdx.x & 63;
  if (n >= N) return;
  const unsigned short* hp = h1 + (size_t)n * 1024 + lane * 16;
  union { bf16x8 v; unsigned short u[8]; } h0, h1v, s0, s1, d0, d1;
  h0.v = *(const bf16x8*)hp;
  h1v.v = *(const bf16x8*)(hp + 8);
  s0.v = *(const bf16x8*)(a_src + lane * 16);
  s1.v = *(const bf16x8*)(a_src + lane * 16 + 8);
  d0.v = *(const bf16x8*)(a_dst + lane * 16);
  d1.v = *(const bf16x8*)(a_dst + lane * 16 + 8);
  float vs = 0.f, vd = 0.f;
#pragma unroll
  for (int j = 0; j < 8; ++j) {
    float a = bf2f(h0.u[j]), b = bf2f(h1v.u[j]);
    vs += a * bf2f(s0.u[j]) + b * bf2f(s1.u[j]);
    vd += a * bf2f(d0.u[j]) + b * bf2f(d1.u[j]);
  }
  vs += __shfl_xor(vs, 1, 64); vd += __shfl_xor(vd, 1, 64);
  vs += __shfl_xor(vs, 2, 64); vd += __shfl_xor(vd, 2, 64);
  vs += __shfl_xor(vs, 4, 64); vd += __shfl_xor(vd, 4, 64);
  if ((lane & 7) == 0) {
    int h = lane >> 3;
    s_src[n * 8 + h] = vs;
    s_dst[n * 8 + h] = vd;
  }
}

// Layer-2 scores: h2 fp32, H=1.
__global__ __launch_bounds__(256) void scores2_f32(
    const float* __restrict__ h2, const unsigned short* __restrict__ a_src,
    const unsigned short* __restrict__ a_dst, float* __restrict__ s_src,
    float* __restrict__ s_dst, int N) {
  int w = blockIdx.x * 4 + (threadIdx.x >> 6);
  int lane = threadIdx.x & 63;
  if (w >= N) return;
  float2 hv = *(const float2*)(h2 + (size_t)w * 128 + lane * 2);
  unsigned int av = *(const unsigned int*)(a_src + lane * 2);
  unsigned int dv = *(const unsigned int*)(a_dst + lane * 2);
  float vs = hv.x * bf2f(av & 0xffff) + hv.y * bf2f(av >> 16);
  float vd = hv.x * bf2f(dv & 0xffff) + hv.y * bf2f(dv >> 16);
#pragma unroll
  for (int off = 32; off > 0; off >>= 1) {
    vs += __shfl_down(vs, off, 64);
    vd += __shfl_down(vd, off, 64);
  }
  if (lane == 0) {
    s_src[w] = vs;
    s_dst[w] = vd;
  }
}

// ---------------------------------------------------------------------------
// Per-edge softmax numerators, computed ONCE per (edge, head).
// ---------------------------------------------------------------------------
__global__ __launch_bounds__(256) void edge_w1(
    const int* __restrict__ srcs, const int* __restrict__ dsts,
    const float* __restrict__ ssrc, const float* __restrict__ sdst,
    float* __restrict__ ew, int E8) {
  int t = blockIdx.x * 256 + threadIdx.x;
  if (t >= E8) return;
  int p = t >> 3, h = t & 7;
  float v = ssrc[srcs[p] * 8 + h] + sdst[dsts[p] * 8 + h];
  v = v > 0.f ? v : NEG_SLOPE * v;
  ew[t] = __expf(v);
}

__global__ __launch_bounds__(256) void edge_w2(
    const int* __restrict__ srcs, const int* __restrict__ dsts,
    const float* __restrict__ ssrc, const float* __restrict__ sdst,
    float* __restrict__ ew2, int E) {
  int p = blockIdx.x * 256 + threadIdx.x;
  if (p >= E) return;
  float v = ssrc[srcs[p]] + sdst[dsts[p]];
  v = v > 0.f ? v : NEG_SLOPE * v;
  ew2[p] = __expf(v);
}

// ---------------------------------------------------------------------------
// Layer-1 aggregation (CSR, block per dst node, 256 threads, 4 ch/thread).
// ---------------------------------------------------------------------------
__global__ __launch_bounds__(256) void agg1_csr(
    const int* __restrict__ offsets, const int* __restrict__ srcs,
    const unsigned short* __restrict__ h1, const float* __restrict__ ew,
    const unsigned short* __restrict__ b1, unsigned short* __restrict__ h1n) {
  int n = blockIdx.x;
  int j = threadIdx.x;
  int c = j * 4;
  int h = c >> 7;
  int beg = offsets[n], end = offsets[n + 1];
  float a0 = 0.f, a1 = 0.f, a2 = 0.f, a3 = 0.f, wsum = 0.f;
  for (int p = beg; p < end; ++p) {
    int s = srcs[p];
    float w = ew[p * 8 + h];
    wsum += w;
    ushort4 u = *(const ushort4*)(h1 + (size_t)s * 1024 + c);
    a0 = fmaf(bf2f(u.x), w, a0);
    a1 = fmaf(bf2f(u.y), w, a1);
    a2 = fmaf(bf2f(u.z), w, a2);
    a3 = fmaf(bf2f(u.w), w, a3);
  }
  float inv = 1.0f / (wsum + 1e-16f);
  ushort4 bb = *(const ushort4*)(b1 + c);
  ushort4 o;
  o.x = f2bf(a0 * inv + bf2f(bb.x));
  o.y = f2bf(a1 * inv + bf2f(bb.y));
  o.z = f2bf(a2 * inv + bf2f(bb.z));
  o.w = f2bf(a3 * inv + bf2f(bb.w));
  *(ushort4*)(h1n + (size_t)n * 1024 + c) = o;
}

// ---------------------------------------------------------------------------
// BN stats, two-stage, ATOMIC-FREE.
// Stage 1: 256 blocks; block b writes its 1024 sums + 1024 sumsqs to
// part[b][0..2047]. 4-row unroll for MLP.
// ---------------------------------------------------------------------------
__global__ __launch_bounds__(256) void bn_stats_part(
    const unsigned short* __restrict__ h1n, float* __restrict__ part, int N,
    int rowsPerBlock) {
  int b = blockIdx.x;
  int r0 = b * rowsPerBlock;
  int r1 = min(r0 + rowsPerBlock, N);
  int c = threadIdx.x * 4;
  float s0 = 0, s1 = 0, s2 = 0, s3 = 0;
  float q0 = 0, q1 = 0, q2 = 0, q3 = 0;
  int r = r0;
  for (; r + 4 <= r1; r += 4) {
    ushort4 u0 = *(const ushort4*)(h1n + (size_t)(r + 0) * 1024 + c);
    ushort4 u1 = *(const ushort4*)(h1n + (size_t)(r + 1) * 1024 + c);
    ushort4 u2 = *(const ushort4*)(h1n + (size_t)(r + 2) * 1024 + c);
    ushort4 u3 = *(const ushort4*)(h1n + (size_t)(r + 3) * 1024 + c);
    float v;
    v = bf2f(u0.x); s0 += v; q0 += v * v;
    v = bf2f(u0.y); s1 += v; q1 += v * v;
    v = bf2f(u0.z); s2 += v; q2 += v * v;
    v = bf2f(u0.w); s3 += v; q3 += v * v;
    v = bf2f(u1.x); s0 += v; q0 += v * v;
    v = bf2f(u1.y); s1 += v; q1 += v * v;
    v = bf2f(u1.z); s2 += v; q2 += v * v;
    v = bf2f(u1.w); s3 += v; q3 += v * v;
    v = bf2f(u2.x); s0 += v; q0 += v * v;
    v = bf2f(u2.y); s1 += v; q1 += v * v;
    v = bf2f(u2.z); s2 += v; q2 += v * v;
    v = bf2f(u2.w); s3 += v; q3 += v * v;
    v = bf2f(u3.x); s0 += v; q0 += v * v;
    v = bf2f(u3.y); s1 += v; q1 += v * v;
    v = bf2f(u3.z); s2 += v; q2 += v * v;
    v = bf2f(u3.w); s3 += v; q3 += v * v;
  }
  for (; r < r1; ++r) {
    ushort4 u = *(const ushort4*)(h1n + (size_t)r * 1024 + c);
    float v;
    v = bf2f(u.x); s0 += v; q0 += v * v;
    v = bf2f(u.y); s1 += v; q1 += v * v;
    v = bf2f(u.z); s2 += v; q2 += v * v;
    v = bf2f(u.w); s3 += v; q3 += v * v;
  }
  float* pb = part + (size_t)b * 2048;
  pb[c + 0] = s0; pb[c + 1] = s1; pb[c + 2] = s2; pb[c + 3] = s3;
  pb[1024 + c + 0] = q0; pb[1024 + c + 1] = q1;
  pb[1024 + c + 2] = q2; pb[1024 + c + 3] = q3;
}

// Stage 2: reduce nparts partials per channel + finalize scale/shift.
// 4 blocks x 256 threads; channel = global thread id.
__global__ __launch_bounds__(256) void bn_reduce_finalize(
    const float* __restrict__ part, int nparts,
    const unsigned short* __restrict__ gamma,
    const unsigned short* __restrict__ beta, float* __restrict__ scale,
    float* __restrict__ shift, int N) {
  int c = blockIdx.x * 256 + threadIdx.x;  // [0,1024)
  float s = 0.f, q = 0.f;
  for (int b = 0; b < nparts; ++b) {
    s += part[(size_t)b * 2048 + c];
    q += part[(size_t)b * 2048 + 1024 + c];
  }
  float inv_n = 1.0f / (float)N;
  float mu = s * inv_n;
  float var = q * inv_n - mu * mu;
  float sc = bf2f(gamma[c]) * rsqrtf(var + BN_EPS);
  scale[c] = sc;
  shift[c] = bf2f(beta[c]) - mu * sc;
}

// ---------------------------------------------------------------------------
// Layer-2 aggregation (CSR, one wave per dst, 2 ch/lane), ew2 precomputed.
// ---------------------------------------------------------------------------
__global__ __launch_bounds__(64) void agg2_csr(
    const int* __restrict__ offsets, const int* __restrict__ srcs,
    const float* __restrict__ h2, const float* __restrict__ ew2,
    const unsigned short* __restrict__ b2, void* __restrict__ out,
    const int* __restrict__ flags) {
  int n = blockIdx.x;
  int lane = threadIdx.x;
  int c = lane * 2;
  int beg = offsets[n], end = offsets[n + 1];
  float a0 = 0.f, a1 = 0.f, wsum = 0.f;
  for (int p = beg; p < end; ++p) {
    int s = srcs[p];
    float w = ew2[p];
    wsum += w;
    float2 hv = *(const float2*)(h2 + (size_t)s * 128 + c);
    a0 = fmaf(hv.x, w, a0);
    a1 = fmaf(hv.y, w, a1);
  }
  float inv = 1.0f / (wsum + 1e-16f);
  unsigned int bb = *(const unsigned int*)(b2 + c);
  float r0 = a0 * inv + bf2f(bb & 0xffff);
  float r1 = a1 * inv + bf2f(bb >> 16);
  if (flags[0]) {
    unsigned int o = (unsigned int)f2bf(r0) | ((unsigned int)f2bf(r1) << 16);
    *(unsigned int*)((unsigned short*)out + (size_t)n * 128 + c) = o;
  } else {
    *(float2*)((float*)out + (size_t)n * 128 + c) = make_float2(r0, r1);
  }
}

// ---------------------------------------------------------------------------
extern "C" void kernel_launch(void* const* d_in, const int* in_sizes, int n_in,
                              void* d_out, int out_size, void* d_ws,
                              size_t ws_size, hipStream_t stream) {
  const void* x      = d_in[0];
  const int*  ei     = (const int*)d_in[1];
  const void* W1     = d_in[2];
  const void* a_src1 = d_in[3];
  const void* a_dst1 = d_in[4];
  const void* b1     = d_in[5];
  const void* gamma  = d_in[6];
  const void* beta   = d_in[7];
  const void* W2     = d_in[8];
  const void* a_src2 = d_in[9];
  const void* a_dst2 = d_in[10];
  const void* b2     = d_in[11];

  const int N = in_sizes[0] / 128;            // 50000
  const int E = in_sizes[1] / 2;              // 150000
  const int MP = ((N + 127) / 128) * 128;     // 50048
  const int NB = (N + 2047) / 2048;           // scan chunks
  const int NSTAT = 256;                      // bn stage-1 blocks
  const int RPB = (N + NSTAT - 1) / NSTAT;    // rows per stat block

  // ---- workspace layout (bytes) ----
  char* ws = (char*)d_ws;
  size_t off = 0;
  unsigned short* h1  = (unsigned short*)(ws + off); off += (size_t)MP * 1024 * 2;
  char* h1n_base = ws + off;
  unsigned short* h1n = (unsigned short*)h1n_base;   off += (size_t)MP * 1024 * 2;
  float* ssrc1 = (float*)(ws + off); off += (size_t)N * 8 * 4;
  float* sdst1 = (float*)(ws + off); off += (size_t)N * 8 * 4;
  int* offsets = (int*)(ws + off); off += ((size_t)(N + 1) * 4 + 63) & ~63ull;
  int* srcs    = (int*)(ws + off); off += (size_t)E * 4;
  int* dsts    = (int*)(ws + off); off += (size_t)E * 4;
  float* ew    = (float*)(ws + off); off += (size_t)E * 8 * 4;  // ew2 aliases
  float* part  = (float*)(ws + off); off += (size_t)NSTAT * 2048 * 4;  // 2 MB
  unsigned short* W1t = (unsigned short*)(ws + off); off += 131072 * 2;
  unsigned short* W2t = (unsigned short*)(ws + off); off += 131072 * 2;
  unsigned short* as1c = (unsigned short*)(ws + off); off += 1024 * 2;
  unsigned short* ad1c = (unsigned short*)(ws + off); off += 1024 * 2;
  unsigned short* b1c  = (unsigned short*)(ws + off); off += 1024 * 2;
  unsigned short* gmc  = (unsigned short*)(ws + off); off += 1024 * 2;
  unsigned short* btc  = (unsigned short*)(ws + off); off += 1024 * 2;
  unsigned short* as2c = (unsigned short*)(ws + off); off += 128 * 2;
  unsigned short* ad2c = (unsigned short*)(ws + off); off += 128 * 2;
  unsigned short* b2c  = (unsigned short*)(ws + off); off += 128 * 2;
  float* scale = (float*)(ws + off); off += 1024 * 4;
  float* shift = (float*)(ws + off); off += 1024 * 4;
  int* bsum    = (int*)(ws + off); off += 256 * 4;
  int* flags   = (int*)(ws + off); off += 64;
  // Aliases into dead regions (h1n's first ~18.5 MB; all dead before agg1
  // writes h1n; h1n pad rows are at the END of the buffer).
  unsigned short* x_bf = (unsigned short*)h1n_base;
  int* eis    = (int*)(h1n_base + (16u << 20));
  int* eid    = eis + E;
  int* cnt    = eid + E;
  int* cursor = cnt + N;
  // h2 (fp32 [MP][128] = 25.6 MB) aliases h1 (dead after agg1).
  float* h2    = (float*)h1;
  float* ssrc2 = ssrc1;
  float* sdst2 = sdst1;
  float* ew2   = ew;

  // ---- detection + canonicalization ----
  detect_kernel<<<1, 256, 0, stream>>>((const unsigned int*)x,
                                       (const unsigned int*)ei, E, flags);
  canon_x<<<(MP * 128 + 255) / 256, 256, 0, stream>>>(x, x_bf, N * 128,
                                                      MP * 128, flags);
  canon_w_t<<<(131072 + 255) / 256, 256, 0, stream>>>(W1, W1t, 128, 1024, flags);
  canon_w_t<<<(131072 + 255) / 256, 256, 0, stream>>>(W2, W2t, 1024, 128, flags);
  canon_params<<<8, 1024, 0, stream>>>(a_src1, a_dst1, b1, gamma, beta, a_src2,
                                       a_dst2, b2, as1c, ad1c, b1c, gmc, btc,
                                       as2c, ad2c, b2c, flags);
  canon_idx<<<(E + 255) / 256, 256, 0, stream>>>(ei, eis, eid, E, flags);

  // ---- zero init ----
  hipMemsetAsync(cnt, 0, (size_t)N * 4, stream);
  hipMemsetAsync((char*)h1n + (size_t)N * 1024 * 2, 0,
                 (size_t)(MP - N) * 1024 * 2, stream);

  // ---- CSR build (dst-sorted), parallel scan ----
  count_dst<<<(E + 255) / 256, 256, 0, stream>>>(eid, E, cnt);
  scan_p1<<<NB, 256, 0, stream>>>(cnt, bsum, N);
  scan_p2<<<1, 256, 0, stream>>>(bsum, NB);
  scan_p3<<<NB, 256, 0, stream>>>(cnt, bsum, offsets, cursor, N);
  scatter_src<<<(E + 255) / 256, 256, 0, stream>>>(eis, eid, E, cursor, srcs,
                                                   dsts);

  // ---- Layer 1: h1 = x @ W1 (MFMA 128x128, prefetch) ----
  {
    dim3 g(1024 / 128, MP / 128);
    gemm_mfma<false, true><<<g, 256, 0, stream>>>(x_bf, W1t, h1, MP, 1024, 128,
                                                  nullptr, nullptr);
  }
  scores1_v2<<<(N + 3) / 4, 256, 0, stream>>>(h1, as1c, ad1c, ssrc1, sdst1, N);
  edge_w1<<<(E * 8 + 255) / 256, 256, 0, stream>>>(srcs, dsts, ssrc1, sdst1,
                                                   ew, E * 8);
  agg1_csr<<<N, 256, 0, stream>>>(offsets, srcs, h1, ew, b1c, h1n);

  // ---- BN stats (two-stage, atomic-free) ----
  bn_stats_part<<<NSTAT, 256, 0, stream>>>(h1n, part, N, RPB);
  bn_reduce_finalize<<<4, 256, 0, stream>>>(part, NSTAT, gmc, btc, scale,
                                            shift, N);

  // ---- Layer 2: h2 = ELU(BN(h1n)) @ W2 (BN+ELU fused into A staging) ----
  {
    dim3 g(1, MP / 128);
    gemm_mfma<true, false><<<g, 256, 0, stream>>>(h1n, W2t, h2, MP, 128, 1024,
                                                  scale, shift);
  }
  scores2_f32<<<(N + 3) / 4, 256, 0, stream>>>(h2, as2c, ad2c, ssrc2, sdst2, N);
  edge_w2<<<(E + 255) / 256, 256, 0, stream>>>(srcs, dsts, ssrc2, sdst2, ew2, E);
  agg2_csr<<<N, 64, 0, stream>>>(offsets, srcs, h2, ew2, b2c, d_out, flags);
}

// Round 9
// 378.649 us; speedup vs baseline: 1.4059x; 1.1886x over previous
//
#include <hip/hip_runtime.h>
#include <hip/hip_bf16.h>
#include <math.h>

#define NEG_SLOPE 0.2f
#define BN_EPS 1e-5f

typedef short bf16x8 __attribute__((ext_vector_type(8)));
typedef float f32x4 __attribute__((ext_vector_type(4)));

// ---- bf16 helpers (raw ushort payload) ------------------------------------
__device__ __forceinline__ float bf2f(unsigned short u) {
  union { unsigned int i; float f; } v;
  v.i = ((unsigned int)u) << 16;
  return v.f;
}
__device__ __forceinline__ unsigned short f2bf(float f) {
  union { unsigned int i; float f; } v;
  v.f = f;
  unsigned int i = v.i;
  unsigned int r = (i + 0x7fffu + ((i >> 16) & 1u)) >> 16;  // RNE
  return (unsigned short)r;
}

// ---------------------------------------------------------------------------
// Dtype detection: flags[0]=1 if floats are bf16; flags[1]=1 if idx int64.
// ---------------------------------------------------------------------------
__global__ __launch_bounds__(256) void detect_kernel(
    const unsigned int* __restrict__ xw, const unsigned int* __restrict__ eiw,
    int E, int* __restrict__ flags) {
  __shared__ int cnt[2];
  if (threadIdx.x < 2) cnt[threadIdx.x] = 0;
  __syncthreads();
  int t = threadIdx.x;
  int inrange = 0;
  for (int i = t; i < 2048; i += 256) {
    unsigned int e = (xw[i] >> 7) & 0xFFu;
    inrange += (e >= 100u && e <= 135u) ? 1 : 0;
  }
  atomicAdd(&cnt[0], inrange);
  int M = min(1024, E / 2);
  int zeros = 0;
  for (int i = t; i < M; i += 256) zeros += (eiw[2 * i + 1] == 0u) ? 1 : 0;
  atomicAdd(&cnt[1], zeros);
  __syncthreads();
  if (t == 0) {
    flags[0] = (cnt[0] > 1536) ? 1 : 0;
    flags[1] = (cnt[1] > M / 2) ? 1 : 0;
  }
}

__global__ __launch_bounds__(256) void canon_x(
    const void* __restrict__ src, unsigned short* __restrict__ dst, int n_real,
    int n_total, const int* __restrict__ flags) {
  int i = blockIdx.x * 256 + threadIdx.x;
  if (i >= n_total) return;
  unsigned short v = 0;
  if (i < n_real)
    v = flags[0] ? ((const unsigned short*)src)[i]
                 : f2bf(((const float*)src)[i]);
  dst[i] = v;
}

// W [K][N] -> Wt [N][K] bf16.
__global__ __launch_bounds__(256) void canon_w_t(
    const void* __restrict__ src, unsigned short* __restrict__ dst, int Kdim,
    int Ndim, const int* __restrict__ flags) {
  int i = blockIdx.x * 256 + threadIdx.x;
  if (i >= Kdim * Ndim) return;
  int k = i / Ndim, n = i - k * Ndim;
  unsigned short v = flags[0] ? ((const unsigned short*)src)[i]
                              : f2bf(((const float*)src)[i]);
  dst[(size_t)n * Kdim + k] = v;
}

__global__ __launch_bounds__(1024) void canon_params(
    const void* s0, const void* s1, const void* s2, const void* s3,
    const void* s4, const void* s5, const void* s6, const void* s7,
    unsigned short* d0, unsigned short* d1, unsigned short* d2,
    unsigned short* d3, unsigned short* d4, unsigned short* d5,
    unsigned short* d6, unsigned short* d7, const int* __restrict__ flags) {
  int b = blockIdx.x, t = threadIdx.x;
  const void* s;
  unsigned short* d;
  int n;
  switch (b) {
    case 0: s = s0; d = d0; n = 1024; break;
    case 1: s = s1; d = d1; n = 1024; break;
    case 2: s = s2; d = d2; n = 1024; break;
    case 3: s = s3; d = d3; n = 1024; break;
    case 4: s = s4; d = d4; n = 1024; break;
    case 5: s = s5; d = d5; n = 128; break;
    case 6: s = s6; d = d6; n = 128; break;
    default: s = s7; d = d7; n = 128; break;
  }
  if (t < n)
    d[t] = flags[0] ? ((const unsigned short*)s)[t]
                    : f2bf(((const float*)s)[t]);
}

__global__ __launch_bounds__(256) void canon_idx(
    const int* __restrict__ ei, int* __restrict__ eis, int* __restrict__ eid,
    int E, const int* __restrict__ flags) {
  int e = blockIdx.x * 256 + threadIdx.x;
  if (e >= E) return;
  if (flags[1]) {
    eis[e] = ei[2 * (size_t)e];
    eid[e] = ei[2 * (size_t)E + 2 * (size_t)e];
  } else {
    eis[e] = ei[e];
    eid[e] = ei[E + e];
  }
}

// ---------------------------------------------------------------------------
// MFMA GEMM: C[M, gx*128] = A[M,K] @ Bt[N,K]^T. 128x128 tile, BK=32,
// 4 waves (2x2), 16 MFMA/iter, 1-deep register prefetch of next K-slab.
// TRANSFORM_A: ELU(a*scale+shift) at LDS-write time (HW __expf).
// ---------------------------------------------------------------------------
template <bool TRANSFORM_A, bool OUT_BF16>
__global__ __launch_bounds__(256) void gemm_mfma(
    const unsigned short* __restrict__ A, const unsigned short* __restrict__ Bt,
    void* __restrict__ Cv, int M, int N, int K,
    const float* __restrict__ scale, const float* __restrict__ shift) {
  constexpr int BK = 32;
  constexpr int LDA = BK + 8;
  __shared__ unsigned short As[128 * LDA];
  __shared__ unsigned short Bs[128 * LDA];

  const int m0 = blockIdx.y * 128;
  const int n0 = blockIdx.x * 128;
  const int tid = threadIdx.x;
  const int wid = tid >> 6;
  const int lane = tid & 63;
  const int q = lane >> 4;
  const int r = lane & 15;
  const int wm = (wid >> 1) * 64;
  const int wn = (wid & 1) * 64;

  f32x4 acc[4][4] = {};

  const int row0 = (tid * 8) >> 5, col0 = (tid * 8) & 31;
  const int row1 = row0 + 64;

  bf16x8 ra[2], rb[2];
  ra[0] = *(const bf16x8*)(A + (size_t)(m0 + row0) * K + col0);
  ra[1] = *(const bf16x8*)(A + (size_t)(m0 + row1) * K + col0);
  rb[0] = *(const bf16x8*)(Bt + (size_t)(n0 + row0) * K + col0);
  rb[1] = *(const bf16x8*)(Bt + (size_t)(n0 + row1) * K + col0);

  for (int k0 = 0; k0 < K; k0 += BK) {
#pragma unroll
    for (int rd = 0; rd < 2; ++rd) {
      int row = rd ? row1 : row0;
      bf16x8 v = ra[rd];
      if (TRANSFORM_A) {
        float scv[8], shv[8];
        *(float4*)&scv[0] = *(const float4*)(scale + k0 + col0);
        *(float4*)&scv[4] = *(const float4*)(scale + k0 + col0 + 4);
        *(float4*)&shv[0] = *(const float4*)(shift + k0 + col0);
        *(float4*)&shv[4] = *(const float4*)(shift + k0 + col0 + 4);
        union { bf16x8 v; unsigned short u[8]; } p;
        p.v = v;
#pragma unroll
        for (int j = 0; j < 8; ++j) {
          float f = bf2f(p.u[j]) * scv[j] + shv[j];
          f = f > 0.f ? f : (__expf(f) - 1.0f);
          p.u[j] = f2bf(f);
        }
        v = p.v;
      }
      *(bf16x8*)(&As[row * LDA + col0]) = v;
      *(bf16x8*)(&Bs[row * LDA + col0]) = rb[rd];
    }
    __syncthreads();

    int k1 = k0 + BK;
    if (k1 < K) {
      ra[0] = *(const bf16x8*)(A + (size_t)(m0 + row0) * K + k1 + col0);
      ra[1] = *(const bf16x8*)(A + (size_t)(m0 + row1) * K + k1 + col0);
      rb[0] = *(const bf16x8*)(Bt + (size_t)(n0 + row0) * K + k1 + col0);
      rb[1] = *(const bf16x8*)(Bt + (size_t)(n0 + row1) * K + k1 + col0);
    }

    bf16x8 af[4], bfv[4];
#pragma unroll
    for (int mi = 0; mi < 4; ++mi)
      af[mi] = *(const bf16x8*)(&As[(wm + mi * 16 + r) * LDA + q * 8]);
#pragma unroll
    for (int ni = 0; ni < 4; ++ni)
      bfv[ni] = *(const bf16x8*)(&Bs[(wn + ni * 16 + r) * LDA + q * 8]);
#pragma unroll
    for (int mi = 0; mi < 4; ++mi)
#pragma unroll
      for (int ni = 0; ni < 4; ++ni)
        acc[mi][ni] = __builtin_amdgcn_mfma_f32_16x16x32_bf16(
            af[mi], bfv[ni], acc[mi][ni], 0, 0, 0);
    __syncthreads();
  }

#pragma unroll
  for (int mi = 0; mi < 4; ++mi) {
#pragma unroll
    for (int ni = 0; ni < 4; ++ni) {
#pragma unroll
      for (int i = 0; i < 4; ++i) {
        int row = m0 + wm + mi * 16 + q * 4 + i;
        int col = n0 + wn + ni * 16 + r;
        if (OUT_BF16)
          ((unsigned short*)Cv)[(size_t)row * N + col] = f2bf(acc[mi][ni][i]);
        else
          ((float*)Cv)[(size_t)row * N + col] = acc[mi][ni][i];
      }
    }
  }
}

// ---------------------------------------------------------------------------
// CSR build over dst — parallel 3-phase scan.
// ---------------------------------------------------------------------------
__global__ __launch_bounds__(256) void count_dst(const int* __restrict__ eid,
                                                 int E, int* __restrict__ cnt) {
  int e = blockIdx.x * 256 + threadIdx.x;
  if (e < E) atomicAdd(&cnt[eid[e]], 1);
}

__global__ __launch_bounds__(256) void scan_p1(const int* __restrict__ cnt,
                                               int* __restrict__ bsum, int N) {
  __shared__ int sd[256];
  int b = blockIdx.x, t = threadIdx.x;
  int base = b * 2048;
  int s = 0;
  for (int i = t; i < 2048; i += 256) {
    int idx = base + i;
    if (idx < N) s += cnt[idx];
  }
  sd[t] = s;
  __syncthreads();
  for (int o = 128; o > 0; o >>= 1) {
    if (t < o) sd[t] += sd[t + o];
    __syncthreads();
  }
  if (t == 0) bsum[b] = sd[0];
}

__global__ __launch_bounds__(256) void scan_p2(int* __restrict__ bsum, int nb) {
  __shared__ int sd[256];
  int t = threadIdx.x;
  int own = (t < nb) ? bsum[t] : 0;
  sd[t] = own;
  __syncthreads();
  for (int o = 1; o < 256; o <<= 1) {
    int v = (t >= o) ? sd[t - o] : 0;
    __syncthreads();
    sd[t] += v;
    __syncthreads();
  }
  if (t < nb) bsum[t] = sd[t] - own;  // exclusive
}

__global__ __launch_bounds__(256) void scan_p3(
    const int* __restrict__ cnt, const int* __restrict__ bsum,
    int* __restrict__ offsets, int* __restrict__ cursor, int N) {
  __shared__ int sd[256];
  int b = blockIdx.x, t = threadIdx.x;
  int base = b * 2048 + t * 8;
  int c[8];
  int ts = 0;
#pragma unroll
  for (int j = 0; j < 8; ++j) {
    int idx = base + j;
    c[j] = (idx < N) ? cnt[idx] : 0;
    ts += c[j];
  }
  sd[t] = ts;
  __syncthreads();
  for (int o = 1; o < 256; o <<= 1) {
    int v = (t >= o) ? sd[t - o] : 0;
    __syncthreads();
    sd[t] += v;
    __syncthreads();
  }
  int run = bsum[b] + sd[t] - ts;
#pragma unroll
  for (int j = 0; j < 8; ++j) {
    int idx = base + j;
    if (idx < N) {
      offsets[idx] = run;
      cursor[idx] = run;
      run += c[j];
    }
  }
  if (b == gridDim.x - 1 && t == 255) offsets[N] = bsum[b] + sd[255];
}

__global__ __launch_bounds__(256) void scatter_src(
    const int* __restrict__ eis, const int* __restrict__ eid, int E,
    int* __restrict__ cursor, int* __restrict__ srcs, int* __restrict__ dsts) {
  int e = blockIdx.x * 256 + threadIdx.x;
  if (e >= E) return;
  int d = eid[e];
  int pos = atomicAdd(&cursor[d], 1);
  srcs[pos] = eis[e];
  dsts[pos] = d;
}

// ---------------------------------------------------------------------------
// Layer-1 scores, one wave per node: lane covers 16 ch; head = lane>>3.
// ---------------------------------------------------------------------------
__global__ __launch_bounds__(256) void scores1_v2(
    const unsigned short* __restrict__ h1, const unsigned short* __restrict__ a_src,
    const unsigned short* __restrict__ a_dst, float* __restrict__ s_src,
    float* __restrict__ s_dst, int N) {
  int n = blockIdx.x * 4 + (threadIdx.x >> 6);
  int lane = threadIdx.x & 63;
  if (n >= N) return;
  const unsigned short* hp = h1 + (size_t)n * 1024 + lane * 16;
  union { bf16x8 v; unsigned short u[8]; } h0, h1v, s0, s1, d0, d1;
  h0.v = *(const bf16x8*)hp;
  h1v.v = *(const bf16x8*)(hp + 8);
  s0.v = *(const bf16x8*)(a_src + lane * 16);
  s1.v = *(const bf16x8*)(a_src + lane * 16 + 8);
  d0.v = *(const bf16x8*)(a_dst + lane * 16);
  d1.v = *(const bf16x8*)(a_dst + lane * 16 + 8);
  float vs = 0.f, vd = 0.f;
#pragma unroll
  for (int j = 0; j < 8; ++j) {
    float a = bf2f(h0.u[j]), b = bf2f(h1v.u[j]);
    vs += a * bf2f(s0.u[j]) + b * bf2f(s1.u[j]);
    vd += a * bf2f(d0.u[j]) + b * bf2f(d1.u[j]);
  }
  vs += __shfl_xor(vs, 1, 64); vd += __shfl_xor(vd, 1, 64);
  vs += __shfl_xor(vs, 2, 64); vd += __shfl_xor(vd, 2, 64);
  vs += __shfl_xor(vs, 4, 64); vd += __shfl_xor(vd, 4, 64);
  if ((lane & 7) == 0) {
    int h = lane >> 3;
    s_src[n * 8 + h] = vs;
    s_dst[n * 8 + h] = vd;
  }
}

// Layer-2 scores: h2 fp32, H=1.
__global__ __launch_bounds__(256) void scores2_f32(
    const float* __restrict__ h2, const unsigned short* __restrict__ a_src,
    const unsigned short* __restrict__ a_dst, float* __restrict__ s_src,
    float* __restrict__ s_dst, int N) {
  int w = blockIdx.x * 4 + (threadIdx.x >> 6);
  int lane = threadIdx.x & 63;
  if (w >= N) return;
  float2 hv = *(const float2*)(h2 + (size_t)w * 128 + lane * 2);
  unsigned int av = *(const unsigned int*)(a_src + lane * 2);
  unsigned int dv = *(const unsigned int*)(a_dst + lane * 2);
  float vs = hv.x * bf2f(av & 0xffff) + hv.y * bf2f(av >> 16);
  float vd = hv.x * bf2f(dv & 0xffff) + hv.y * bf2f(dv >> 16);
#pragma unroll
  for (int off = 32; off > 0; off >>= 1) {
    vs += __shfl_down(vs, off, 64);
    vd += __shfl_down(vd, off, 64);
  }
  if (lane == 0) {
    s_src[w] = vs;
    s_dst[w] = vd;
  }
}

// ---------------------------------------------------------------------------
// Per-edge softmax numerators, computed ONCE per (edge, head).
// ---------------------------------------------------------------------------
__global__ __launch_bounds__(256) void edge_w1(
    const int* __restrict__ srcs, const int* __restrict__ dsts,
    const float* __restrict__ ssrc, const float* __restrict__ sdst,
    float* __restrict__ ew, int E8) {
  int t = blockIdx.x * 256 + threadIdx.x;
  if (t >= E8) return;
  int p = t >> 3, h = t & 7;
  float v = ssrc[srcs[p] * 8 + h] + sdst[dsts[p] * 8 + h];
  v = v > 0.f ? v : NEG_SLOPE * v;
  ew[t] = __expf(v);
}

__global__ __launch_bounds__(256) void edge_w2(
    const int* __restrict__ srcs, const int* __restrict__ dsts,
    const float* __restrict__ ssrc, const float* __restrict__ sdst,
    float* __restrict__ ew2, int E) {
  int p = blockIdx.x * 256 + threadIdx.x;
  if (p >= E) return;
  float v = ssrc[srcs[p]] + sdst[dsts[p]];
  v = v > 0.f ? v : NEG_SLOPE * v;
  ew2[p] = __expf(v);
}

// ---------------------------------------------------------------------------
// Layer-1 aggregation (CSR, block per dst node, 256 threads, 4 ch/thread).
// ---------------------------------------------------------------------------
__global__ __launch_bounds__(256) void agg1_csr(
    const int* __restrict__ offsets, const int* __restrict__ srcs,
    const unsigned short* __restrict__ h1, const float* __restrict__ ew,
    const unsigned short* __restrict__ b1, unsigned short* __restrict__ h1n) {
  int n = blockIdx.x;
  int j = threadIdx.x;
  int c = j * 4;
  int h = c >> 7;
  int beg = offsets[n], end = offsets[n + 1];
  float a0 = 0.f, a1 = 0.f, a2 = 0.f, a3 = 0.f, wsum = 0.f;
  for (int p = beg; p < end; ++p) {
    int s = srcs[p];
    float w = ew[p * 8 + h];
    wsum += w;
    ushort4 u = *(const ushort4*)(h1 + (size_t)s * 1024 + c);
    a0 = fmaf(bf2f(u.x), w, a0);
    a1 = fmaf(bf2f(u.y), w, a1);
    a2 = fmaf(bf2f(u.z), w, a2);
    a3 = fmaf(bf2f(u.w), w, a3);
  }
  float inv = 1.0f / (wsum + 1e-16f);
  ushort4 bb = *(const ushort4*)(b1 + c);
  ushort4 o;
  o.x = f2bf(a0 * inv + bf2f(bb.x));
  o.y = f2bf(a1 * inv + bf2f(bb.y));
  o.z = f2bf(a2 * inv + bf2f(bb.z));
  o.w = f2bf(a3 * inv + bf2f(bb.w));
  *(ushort4*)(h1n + (size_t)n * 1024 + c) = o;
}

// ---------------------------------------------------------------------------
// BN stats, two-stage, ATOMIC-FREE.
// Stage 1: 256 blocks; block b writes its 1024 sums + 1024 sumsqs to
// part[b][0..2047]. 4-row unroll for MLP.
// ---------------------------------------------------------------------------
__global__ __launch_bounds__(256) void bn_stats_part(
    const unsigned short* __restrict__ h1n, float* __restrict__ part, int N,
    int rowsPerBlock) {
  int b = blockIdx.x;
  int r0 = b * rowsPerBlock;
  int r1 = min(r0 + rowsPerBlock, N);
  int c = threadIdx.x * 4;
  float s0 = 0, s1 = 0, s2 = 0, s3 = 0;
  float q0 = 0, q1 = 0, q2 = 0, q3 = 0;
  int r = r0;
  for (; r + 4 <= r1; r += 4) {
    ushort4 u0 = *(const ushort4*)(h1n + (size_t)(r + 0) * 1024 + c);
    ushort4 u1 = *(const ushort4*)(h1n + (size_t)(r + 1) * 1024 + c);
    ushort4 u2 = *(const ushort4*)(h1n + (size_t)(r + 2) * 1024 + c);
    ushort4 u3 = *(const ushort4*)(h1n + (size_t)(r + 3) * 1024 + c);
    float v;
    v = bf2f(u0.x); s0 += v; q0 += v * v;
    v = bf2f(u0.y); s1 += v; q1 += v * v;
    v = bf2f(u0.z); s2 += v; q2 += v * v;
    v = bf2f(u0.w); s3 += v; q3 += v * v;
    v = bf2f(u1.x); s0 += v; q0 += v * v;
    v = bf2f(u1.y); s1 += v; q1 += v * v;
    v = bf2f(u1.z); s2 += v; q2 += v * v;
    v = bf2f(u1.w); s3 += v; q3 += v * v;
    v = bf2f(u2.x); s0 += v; q0 += v * v;
    v = bf2f(u2.y); s1 += v; q1 += v * v;
    v = bf2f(u2.z); s2 += v; q2 += v * v;
    v = bf2f(u2.w); s3 += v; q3 += v * v;
    v = bf2f(u3.x); s0 += v; q0 += v * v;
    v = bf2f(u3.y); s1 += v; q1 += v * v;
    v = bf2f(u3.z); s2 += v; q2 += v * v;
    v = bf2f(u3.w); s3 += v; q3 += v * v;
  }
  for (; r < r1; ++r) {
    ushort4 u = *(const ushort4*)(h1n + (size_t)r * 1024 + c);
    float v;
    v = bf2f(u.x); s0 += v; q0 += v * v;
    v = bf2f(u.y); s1 += v; q1 += v * v;
    v = bf2f(u.z); s2 += v; q2 += v * v;
    v = bf2f(u.w); s3 += v; q3 += v * v;
  }
  float* pb = part + (size_t)b * 2048;
  pb[c + 0] = s0; pb[c + 1] = s1; pb[c + 2] = s2; pb[c + 3] = s3;
  pb[1024 + c + 0] = q0; pb[1024 + c + 1] = q1;
  pb[1024 + c + 2] = q2; pb[1024 + c + 3] = q3;
}

// Stage 2: one WAVE per channel (256 blocks x 4 waves). Lane l covers
// partial blocks l, l+64, l+128, l+192; butterfly-reduce; lane 0 finalizes.
__global__ __launch_bounds__(256) void bn_reduce_finalize(
    const float* __restrict__ part, int nparts,
    const unsigned short* __restrict__ gamma,
    const unsigned short* __restrict__ beta, float* __restrict__ scale,
    float* __restrict__ shift, int N) {
  int c = blockIdx.x * 4 + (threadIdx.x >> 6);  // channel [0,1024)
  int lane = threadIdx.x & 63;
  float s = 0.f, q = 0.f;
  for (int b = lane; b < nparts; b += 64) {
    s += part[(size_t)b * 2048 + c];
    q += part[(size_t)b * 2048 + 1024 + c];
  }
#pragma unroll
  for (int o = 32; o > 0; o >>= 1) {
    s += __shfl_xor(s, o, 64);
    q += __shfl_xor(q, o, 64);
  }
  if (lane == 0) {
    float inv_n = 1.0f / (float)N;
    float mu = s * inv_n;
    float var = q * inv_n - mu * mu;
    float sc = bf2f(gamma[c]) * rsqrtf(var + BN_EPS);
    scale[c] = sc;
    shift[c] = bf2f(beta[c]) - mu * sc;
  }
}

// ---------------------------------------------------------------------------
// Layer-2 aggregation (CSR, one wave per dst, 2 ch/lane), ew2 precomputed.
// ---------------------------------------------------------------------------
__global__ __launch_bounds__(64) void agg2_csr(
    const int* __restrict__ offsets, const int* __restrict__ srcs,
    const float* __restrict__ h2, const float* __restrict__ ew2,
    const unsigned short* __restrict__ b2, void* __restrict__ out,
    const int* __restrict__ flags) {
  int n = blockIdx.x;
  int lane = threadIdx.x;
  int c = lane * 2;
  int beg = offsets[n], end = offsets[n + 1];
  float a0 = 0.f, a1 = 0.f, wsum = 0.f;
  for (int p = beg; p < end; ++p) {
    int s = srcs[p];
    float w = ew2[p];
    wsum += w;
    float2 hv = *(const float2*)(h2 + (size_t)s * 128 + c);
    a0 = fmaf(hv.x, w, a0);
    a1 = fmaf(hv.y, w, a1);
  }
  float inv = 1.0f / (wsum + 1e-16f);
  unsigned int bb = *(const unsigned int*)(b2 + c);
  float r0 = a0 * inv + bf2f(bb & 0xffff);
  float r1 = a1 * inv + bf2f(bb >> 16);
  if (flags[0]) {
    unsigned int o = (unsigned int)f2bf(r0) | ((unsigned int)f2bf(r1) << 16);
    *(unsigned int*)((unsigned short*)out + (size_t)n * 128 + c) = o;
  } else {
    *(float2*)((float*)out + (size_t)n * 128 + c) = make_float2(r0, r1);
  }
}

// ---------------------------------------------------------------------------
extern "C" void kernel_launch(void* const* d_in, const int* in_sizes, int n_in,
                              void* d_out, int out_size, void* d_ws,
                              size_t ws_size, hipStream_t stream) {
  const void* x      = d_in[0];
  const int*  ei     = (const int*)d_in[1];
  const void* W1     = d_in[2];
  const void* a_src1 = d_in[3];
  const void* a_dst1 = d_in[4];
  const void* b1     = d_in[5];
  const void* gamma  = d_in[6];
  const void* beta   = d_in[7];
  const void* W2     = d_in[8];
  const void* a_src2 = d_in[9];
  const void* a_dst2 = d_in[10];
  const void* b2     = d_in[11];

  const int N = in_sizes[0] / 128;            // 50000
  const int E = in_sizes[1] / 2;              // 150000
  const int MP = ((N + 127) / 128) * 128;     // 50048
  const int NB = (N + 2047) / 2048;           // scan chunks
  const int NSTAT = 256;                      // bn stage-1 blocks
  const int RPB = (N + NSTAT - 1) / NSTAT;    // rows per stat block

  // ---- workspace layout (bytes) ----
  char* ws = (char*)d_ws;
  size_t off = 0;
  unsigned short* h1  = (unsigned short*)(ws + off); off += (size_t)MP * 1024 * 2;
  char* h1n_base = ws + off;
  unsigned short* h1n = (unsigned short*)h1n_base;   off += (size_t)MP * 1024 * 2;
  float* ssrc1 = (float*)(ws + off); off += (size_t)N * 8 * 4;
  float* sdst1 = (float*)(ws + off); off += (size_t)N * 8 * 4;
  int* offsets = (int*)(ws + off); off += ((size_t)(N + 1) * 4 + 63) & ~63ull;
  int* srcs    = (int*)(ws + off); off += (size_t)E * 4;
  int* dsts    = (int*)(ws + off); off += (size_t)E * 4;
  float* ew    = (float*)(ws + off); off += (size_t)E * 8 * 4;  // ew2 aliases
  float* part  = (float*)(ws + off); off += (size_t)NSTAT * 2048 * 4;  // 2 MB
  unsigned short* W1t = (unsigned short*)(ws + off); off += 131072 * 2;
  unsigned short* W2t = (unsigned short*)(ws + off); off += 131072 * 2;
  unsigned short* as1c = (unsigned short*)(ws + off); off += 1024 * 2;
  unsigned short* ad1c = (unsigned short*)(ws + off); off += 1024 * 2;
  unsigned short* b1c  = (unsigned short*)(ws + off); off += 1024 * 2;
  unsigned short* gmc  = (unsigned short*)(ws + off); off += 1024 * 2;
  unsigned short* btc  = (unsigned short*)(ws + off); off += 1024 * 2;
  unsigned short* as2c = (unsigned short*)(ws + off); off += 128 * 2;
  unsigned short* ad2c = (unsigned short*)(ws + off); off += 128 * 2;
  unsigned short* b2c  = (unsigned short*)(ws + off); off += 128 * 2;
  float* scale = (float*)(ws + off); off += 1024 * 4;
  float* shift = (float*)(ws + off); off += 1024 * 4;
  int* bsum    = (int*)(ws + off); off += 256 * 4;
  int* flags   = (int*)(ws + off); off += 64;
  // Aliases into dead regions (h1n's first ~18.5 MB; all dead before agg1
  // writes h1n; h1n pad rows are at the END of the buffer).
  unsigned short* x_bf = (unsigned short*)h1n_base;
  int* eis    = (int*)(h1n_base + (16u << 20));
  int* eid    = eis + E;
  int* cnt    = eid + E;
  int* cursor = cnt + N;
  // h2 (fp32 [MP][128] = 25.6 MB) aliases h1 (dead after agg1).
  float* h2    = (float*)h1;
  float* ssrc2 = ssrc1;
  float* sdst2 = sdst1;
  float* ew2   = ew;

  // ---- detection + canonicalization ----
  detect_kernel<<<1, 256, 0, stream>>>((const unsigned int*)x,
                                       (const unsigned int*)ei, E, flags);
  canon_x<<<(MP * 128 + 255) / 256, 256, 0, stream>>>(x, x_bf, N * 128,
                                                      MP * 128, flags);
  canon_w_t<<<(131072 + 255) / 256, 256, 0, stream>>>(W1, W1t, 128, 1024, flags);
  canon_w_t<<<(131072 + 255) / 256, 256, 0, stream>>>(W2, W2t, 1024, 128, flags);
  canon_params<<<8, 1024, 0, stream>>>(a_src1, a_dst1, b1, gamma, beta, a_src2,
                                       a_dst2, b2, as1c, ad1c, b1c, gmc, btc,
                                       as2c, ad2c, b2c, flags);
  canon_idx<<<(E + 255) / 256, 256, 0, stream>>>(ei, eis, eid, E, flags);

  // ---- zero init ----
  hipMemsetAsync(cnt, 0, (size_t)N * 4, stream);
  hipMemsetAsync((char*)h1n + (size_t)N * 1024 * 2, 0,
                 (size_t)(MP - N) * 1024 * 2, stream);

  // ---- CSR build (dst-sorted), parallel scan ----
  count_dst<<<(E + 255) / 256, 256, 0, stream>>>(eid, E, cnt);
  scan_p1<<<NB, 256, 0, stream>>>(cnt, bsum, N);
  scan_p2<<<1, 256, 0, stream>>>(bsum, NB);
  scan_p3<<<NB, 256, 0, stream>>>(cnt, bsum, offsets, cursor, N);
  scatter_src<<<(E + 255) / 256, 256, 0, stream>>>(eis, eid, E, cursor, srcs,
                                                   dsts);

  // ---- Layer 1: h1 = x @ W1 (MFMA 128x128, prefetch) ----
  {
    dim3 g(1024 / 128, MP / 128);
    gemm_mfma<false, true><<<g, 256, 0, stream>>>(x_bf, W1t, h1, MP, 1024, 128,
                                                  nullptr, nullptr);
  }
  scores1_v2<<<(N + 3) / 4, 256, 0, stream>>>(h1, as1c, ad1c, ssrc1, sdst1, N);
  edge_w1<<<(E * 8 + 255) / 256, 256, 0, stream>>>(srcs, dsts, ssrc1, sdst1,
                                                   ew, E * 8);
  agg1_csr<<<N, 256, 0, stream>>>(offsets, srcs, h1, ew, b1c, h1n);

  // ---- BN stats (two-stage, atomic-free; stage 2 wave-per-channel) ----
  bn_stats_part<<<NSTAT, 256, 0, stream>>>(h1n, part, N, RPB);
  bn_reduce_finalize<<<256, 256, 0, stream>>>(part, NSTAT, gmc, btc, scale,
                                              shift, N);

  // ---- Layer 2: h2 = ELU(BN(h1n)) @ W2 (BN+ELU fused into A staging) ----
  {
    dim3 g(1, MP / 128);
    gemm_mfma<true, false><<<g, 256, 0, stream>>>(h1n, W2t, h2, MP, 128, 1024,
                                                  scale, shift);
  }
  scores2_f32<<<(N + 3) / 4, 256, 0, stream>>>(h2, as2c, ad2c, ssrc2, sdst2, N);
  edge_w2<<<(E + 255) / 256, 256, 0, stream>>>(srcs, dsts, ssrc2, sdst2, ew2, E);
  agg2_csr<<<N, 64, 0, stream>>>(offsets, srcs, h2, ew2, b2c, d_out, flags);
}